// Round 4
// baseline (27.902 us; speedup 1.0000x reference)
//
#include <hip/hip_runtime.h>
#include <hip/hip_bf16.h>

// S=128, Q=8192, H=230
//   logits[s,q] = a[s] + (c[q]+b) - 2*sum_k wx[s,k]*y[q,k]
//   a[s]=sum w*x^2 (f32), c[q]=sum w*y^2 (f32, exact), dot via bf16 MFMA.
// prep: builds xwb[128][256] bf16, ybf[8192][256] bf16 (zero-padded),
//       asum[128] f32, cqb[8192] f32 (= c[q]+b).
// main: barrier-free; each wave = 16s x 16q MFMA tile streamed from L2/L3.
// All reductions fixed-order (graph replay must be bitwise identical).

#define S_DIM 128
#define Q_DIM 8192
#define H_DIM 230
#define K2    256
#define SQ    (S_DIM * Q_DIM)
#define NMAIN 2048             // main grid: 512 q-tiles x 4 s-splits

using short8 = __attribute__((ext_vector_type(8))) short;   // 8 bf16
using f32x4  = __attribute__((ext_vector_type(4))) float;

// ---------------- Kernel 1: prep ----------------
// grid = 128 + 256 = 384, block = 256.
// blocks [0,128): xwb row s + asum[s].
// blocks [128,384): 32 q-rows each -> ybf (bf16, padded) + cqb[q]=c[q]+b.
__global__ __launch_bounds__(256) void prep_kernel(
    const float* __restrict__ x, const float* __restrict__ y,
    const float* __restrict__ w, const float* __restrict__ bptr,
    __hip_bfloat16* __restrict__ xwb, __hip_bfloat16* __restrict__ ybf,
    float* __restrict__ asum, float* __restrict__ cqb)
{
    const int tid = threadIdx.x, bid = blockIdx.x;

    if (bid < S_DIM) {
        // ---- x side ----
        __shared__ float lred[4];
        const int s = bid;
        float xv = 0.f, wv = 0.f;
        if (tid < H_DIM) { xv = x[s * H_DIM + tid]; wv = w[tid]; }
        float wx = wv * xv;
        xwb[s * K2 + tid] = __float2bfloat16(wx);   // 0 for tid>=230

        float p = wx * xv;                          // w*x^2
        #pragma unroll
        for (int off = 32; off >= 1; off >>= 1) p += __shfl_down(p, off, 64);
        if ((tid & 63) == 0) lred[tid >> 6] = p;
        __syncthreads();
        if (tid == 0) asum[s] = lred[0] + lred[1] + lred[2] + lred[3];
    } else {
        // ---- y side: 32 rows starting at q0 ----
        __shared__ float cpart[8][33];
        const int q0 = (bid - S_DIM) * 32;

        // bf16 copy, coalesced float4 reads of the contiguous 32x230 span
        const float4* src = reinterpret_cast<const float4*>(y + (size_t)q0 * H_DIM);
        for (int i4 = tid; i4 < (32 * H_DIM) / 4; i4 += 256) {
            float4 v = src[i4];
            float vv[4] = {v.x, v.y, v.z, v.w};
            int ee = i4 * 4;
            #pragma unroll
            for (int j = 0; j < 4; ++j) {
                int e = ee + j;
                int r = e / H_DIM;
                int c = e - r * H_DIM;
                ybf[(size_t)(q0 + r) * K2 + c] = __float2bfloat16(vv[j]);
            }
        }
        // zero-pad k = 230..255
        for (int idx = tid; idx < 32 * (K2 - H_DIM); idx += 256) {
            int r = idx / (K2 - H_DIM);
            int c = H_DIM + idx - r * (K2 - H_DIM);
            ybf[(size_t)(q0 + r) * K2 + c] = __float2bfloat16(0.0f);
        }

        // c[q] = sum_k w[k]*y[q,k]^2 (f32 exact), 8 threads per row
        const int r = tid & 31, part = tid >> 5;
        const int k0 = part * 29;
        const int k1 = (k0 + 29 < H_DIM) ? k0 + 29 : H_DIM;
        float p = 0.f;
        const float* yrow = y + (size_t)(q0 + r) * H_DIM;
        for (int k = k0; k < k1; ++k) {
            float v = yrow[k];
            p = fmaf(w[k] * v, v, p);
        }
        cpart[part][r] = p;
        __syncthreads();
        if (tid < 32) {
            float c = 0.f;
            #pragma unroll
            for (int pp = 0; pp < 8; ++pp) c += cpart[pp][tid];
            cqb[q0 + tid] = c + bptr[0];
        }
    }
}

// ---------------- Kernel 2: main (barrier-free MFMA + sigmoid + BCE) ----------------
// grid = 2048, block = 128 (2 waves). qt = bid&511 (q-tile of 16),
// ss = bid>>9 (s-split of 32; co-XCD for L2 sharing of ybf tile).
// Wave wid: s in [ss*32 + wid*16, +16), one 16x16x(256) MFMA chain.
__global__ __launch_bounds__(128) void main_kernel(
    const int* __restrict__ label,
    const __hip_bfloat16* __restrict__ xwb, const __hip_bfloat16* __restrict__ ybf,
    const float* __restrict__ asum, const float* __restrict__ cqb,
    float* __restrict__ out, float* __restrict__ lossws)
{
    __shared__ float lred[2];
    const int tid = threadIdx.x;
    const int wid = tid >> 6, l = tid & 63;
    const int lm = l & 15, lh = l >> 4;            // col / k-group
    const int bid = blockIdx.x;
    const int qt = bid & 511, ss = bid >> 9;
    const int q0 = qt * 16, s0 = ss * 32 + wid * 16;
    const int qg = q0 + lm;

    // ---- prefetch epilogue operands (hide label HBM latency under MFMA) ----
    const float cqv = cqb[qg];
    const size_t obase = (size_t)(s0 + lh * 4) * Q_DIM + qg;
    int labs[4]; float asv[4];
    #pragma unroll
    for (int r = 0; r < 4; ++r) labs[r] = label[obase + (size_t)r * Q_DIM];
    #pragma unroll
    for (int r = 0; r < 4; ++r) asv[r] = asum[s0 + lh * 4 + r];

    // ---- MFMA k-loop: A row = s0+lm, B col = qg, k = ks*32 + lh*8 + e ----
    const short* A = reinterpret_cast<const short*>(xwb) + (s0 + lm) * K2 + lh * 8;
    const short* B = reinterpret_cast<const short*>(ybf) + (size_t)qg * K2 + lh * 8;
    f32x4 acc = {0.f, 0.f, 0.f, 0.f};
    #pragma unroll
    for (int ks = 0; ks < K2 / 32; ++ks) {
        short8 a  = *reinterpret_cast<const short8*>(A + ks * 32);
        short8 bf = *reinterpret_cast<const short8*>(B + ks * 32);
        acc = __builtin_amdgcn_mfma_f32_16x16x32_bf16(a, bf, acc, 0, 0, 0);
    }

    // ---- epilogue: D row = lh*4+r (s), col = lm (q) ----
    float lsum = 0.f;
    #pragma unroll
    for (int r = 0; r < 4; ++r) {
        float z = asv[r] + cqv - 2.0f * acc[r];
        float sc = 1.0f / (1.0f + __expf(-z));
        out[obase + (size_t)r * Q_DIM] = sc;
        float lab = (float)labs[r];
        float bce = fmaxf(z, 0.f) - z * lab + log1pf(__expf(-fabsf(z)));
        lsum += bce;
    }
    #pragma unroll
    for (int off = 32; off >= 1; off >>= 1) lsum += __shfl_down(lsum, off, 64);
    if (l == 0) lred[wid] = lsum;
    __syncthreads();
    if (tid == 0) lossws[bid] = lred[0] + lred[1];
}

// ---------------- Kernel 3: deterministic loss reduce ----------------
// 1 block, 256 threads; fixed-order reduce of NMAIN=2048 partials.
__global__ __launch_bounds__(256) void loss_reduce_kernel(
    const float* __restrict__ lossws, float* __restrict__ out)
{
    __shared__ float lred[4];
    const int tid = threadIdx.x;
    float p = 0.f;
    #pragma unroll
    for (int i = 0; i < NMAIN / 256; ++i) p += lossws[tid + 256 * i];
    #pragma unroll
    for (int off = 32; off >= 1; off >>= 1) p += __shfl_down(p, off, 64);
    if ((tid & 63) == 0) lred[tid >> 6] = p;
    __syncthreads();
    if (tid == 0)
        out[SQ] = (lred[0] + lred[1] + lred[2] + lred[3]) * (1.0f / (float)SQ);
}

extern "C" void kernel_launch(void* const* d_in, const int* in_sizes, int n_in,
                              void* d_out, int out_size, void* d_ws, size_t ws_size,
                              hipStream_t stream) {
    const float* x = (const float*)d_in[0];     // [128,230]
    const float* y = (const float*)d_in[1];     // [8192,230]
    const int* label = (const int*)d_in[2];     // [128,8192]
    const float* w = (const float*)d_in[3];     // [230]
    const float* b = (const float*)d_in[4];     // [1]
    float* out = (float*)d_out;                 // [128*8192 + 1]

    char* ws = (char*)d_ws;
    __hip_bfloat16* xwb = (__hip_bfloat16*)ws;                   // 128*256*2 = 64 KB
    __hip_bfloat16* ybf = (__hip_bfloat16*)(ws + 64 * 1024);     // 8192*256*2 = 4 MB
    float* asum   = (float*)(ws + 64 * 1024 + 4 * 1024 * 1024);  // [128]
    float* cqb    = asum + S_DIM;                                // [8192]
    float* lossws = cqb + Q_DIM;                                 // [2048]

    prep_kernel<<<S_DIM + Q_DIM / 32, 256, 0, stream>>>(x, y, w, b, xwb, ybf, asum, cqb);
    main_kernel<<<NMAIN, 128, 0, stream>>>(label, xwb, ybf, asum, cqb, out, lossws);
    loss_reduce_kernel<<<1, 256, 0, stream>>>(lossws, out);
}